// Round 1
// baseline (380.168 us; speedup 1.0000x reference)
//
#include <hip/hip_runtime.h>
#include <math.h>

// ---------------------------------------------------------------------------
// Problem constants (shapes come from the reference; sizes re-derived at launch)
//   N=50000 nodes, E=400000 edges (+N self loops), EL=100000 label pairs
//   H=8 heads, IN=128, HID=32, OUT=32  -> H*C = 256 columns in both GEMMs
// ---------------------------------------------------------------------------

// ======================= GEMM + attention logits ===========================
// Computes xh = X @ W  (n x K) @ (K x 256), plus
//   aS[n][h] = sum_c xh[n][h*32+c] * attS[h][c]
//   aD[n][h] = sum_c xh[n][h*32+c] * attD[h][c]
// Block: 256 threads -> tile of 16 rows x 256 cols; thread = 4 rows x 4 cols.
template<int K>
__global__ __launch_bounds__(256) void gemm_att(
    const float* __restrict__ X, const float* __restrict__ W,
    const float* __restrict__ attS, const float* __restrict__ attD,
    float* __restrict__ xh, float* __restrict__ aS, float* __restrict__ aD,
    int n)
{
  __shared__ float xs[16][K];     // 16 rows of X
  __shared__ float wsm[32][256];  // K-chunk of W (32 rows)

  const int tid = threadIdx.x;
  const int tc  = tid & 63;   // column group: cols tc*4 .. tc*4+3
  const int tr  = tid >> 6;   // row group: rows tr*4 .. tr*4+3
  const int rowBase = blockIdx.x * 16;

  // --- load X tile (zero-pad OOB rows) ---
  constexpr int XF4 = (16 * K) / 4;
  for (int i = tid; i < XF4; i += 256) {
    const int r  = i / (K / 4);
    const int c4 = i % (K / 4);
    const int row = rowBase + r;
    float4 v = make_float4(0.f, 0.f, 0.f, 0.f);
    if (row < n) v = reinterpret_cast<const float4*>(X + (size_t)row * K)[c4];
    reinterpret_cast<float4*>(&xs[r][0])[c4] = v;
  }

  float acc[4][4] = {};

  constexpr int NCHUNK = K / 32;
  for (int kc = 0; kc < NCHUNK; ++kc) {
    __syncthreads();
    // load W chunk: rows kc*32 .. kc*32+31, 256 cols = 2048 float4
    #pragma unroll
    for (int p = 0; p < 8; ++p) {
      const int i4 = p * 256 + tid;
      const int k  = i4 >> 6;
      const int c4 = i4 & 63;
      reinterpret_cast<float4*>(&wsm[k][0])[c4] =
          reinterpret_cast<const float4*>(W + (size_t)(kc * 32 + k) * 256)[c4];
    }
    __syncthreads();

    #pragma unroll
    for (int k4 = 0; k4 < 8; ++k4) {
      float4 wv[4];
      #pragma unroll
      for (int kk = 0; kk < 4; ++kk)
        wv[kk] = reinterpret_cast<float4*>(&wsm[k4 * 4 + kk][0])[tc];
      #pragma unroll
      for (int r = 0; r < 4; ++r) {
        const float4 xv = reinterpret_cast<float4*>(&xs[tr * 4 + r][0])[kc * 8 + k4];
        const float xk[4] = {xv.x, xv.y, xv.z, xv.w};
        #pragma unroll
        for (int kk = 0; kk < 4; ++kk) {
          acc[r][0] += xk[kk] * wv[kk].x;
          acc[r][1] += xk[kk] * wv[kk].y;
          acc[r][2] += xk[kk] * wv[kk].z;
          acc[r][3] += xk[kk] * wv[kk].w;
        }
      }
    }
  }

  // --- epilogue: store xh, reduce attention logits over c within head ---
  const int h    = tc >> 3;         // head of this thread's 4 columns
  const int csub = (tc & 7) * 4;    // c offset within head
  float sa[4], da[4];
  #pragma unroll
  for (int j = 0; j < 4; ++j) {
    sa[j] = attS[h * 32 + csub + j];
    da[j] = attD[h * 32 + csub + j];
  }

  #pragma unroll
  for (int r = 0; r < 4; ++r) {
    const int row = rowBase + tr * 4 + r;
    if (row >= n) continue;
    float4 o;
    o.x = acc[r][0]; o.y = acc[r][1]; o.z = acc[r][2]; o.w = acc[r][3];
    reinterpret_cast<float4*>(xh + (size_t)row * 256)[tc] = o;

    float ps = acc[r][0] * sa[0] + acc[r][1] * sa[1] + acc[r][2] * sa[2] + acc[r][3] * sa[3];
    float pd = acc[r][0] * da[0] + acc[r][1] * da[1] + acc[r][2] * da[2] + acc[r][3] * da[3];
    #pragma unroll
    for (int msk = 1; msk <= 4; msk <<= 1) {
      ps += __shfl_xor(ps, msk);
      pd += __shfl_xor(pd, msk);
    }
    if ((tc & 7) == 0) {
      aS[(size_t)row * 8 + h] = ps;
      aD[(size_t)row * 8 + h] = pd;
    }
  }
}

// ============================ CSR construction =============================
__global__ void count_kernel(const int* __restrict__ ei, int* __restrict__ deg,
                             int E_, int n) {
  const int i = blockIdx.x * blockDim.x + threadIdx.x;
  const int Et = E_ + n;
  if (i >= Et) return;
  const int dst = (i < E_) ? ei[E_ + i] : (i - E_);
  atomicAdd(&deg[dst], 1);
}

__global__ void scan_kernel(const int* __restrict__ deg, int* __restrict__ off,
                            int* __restrict__ cursor, int n) {
  __shared__ int sd[1024];
  __shared__ int s_run;
  const int tid = threadIdx.x;
  if (tid == 0) s_run = 0;
  __syncthreads();
  constexpr int PT = 8, CH = 1024 * PT;
  for (int base = 0; base < n; base += CH) {
    int v[PT];
    int tsum = 0;
    #pragma unroll
    for (int j = 0; j < PT; ++j) {
      const int idx = base + tid * PT + j;
      v[j] = (idx < n) ? deg[idx] : 0;
      tsum += v[j];
    }
    sd[tid] = tsum;
    __syncthreads();
    for (int o = 1; o < 1024; o <<= 1) {
      const int t = (tid >= o) ? sd[tid - o] : 0;
      __syncthreads();
      sd[tid] += t;
      __syncthreads();
    }
    int start = s_run + sd[tid] - tsum;
    #pragma unroll
    for (int j = 0; j < PT; ++j) {
      const int idx = base + tid * PT + j;
      if (idx < n) { off[idx] = start; cursor[idx] = start; }
      start += v[j];
    }
    __syncthreads();
    if (tid == 0) s_run += sd[1023];
    __syncthreads();
  }
}

__global__ void scatter_kernel(const int* __restrict__ ei, int* __restrict__ cursor,
                               int* __restrict__ csr_src, int E_, int n) {
  const int i = blockIdx.x * blockDim.x + threadIdx.x;
  const int Et = E_ + n;
  if (i >= Et) return;
  int src, dst;
  if (i < E_) { src = ei[i]; dst = ei[E_ + i]; }
  else        { src = i - E_; dst = i - E_; }
  const int pos = atomicAdd(&cursor[dst], 1);
  csr_src[pos] = src;
}

// ===================== per-destination gather + softmax ====================
// One wave (64 lanes) per node. Lane owns 4 consecutive channels of the
// flattened 256 = (h*32+c): k = lane*4+j -> head = lane>>3.
// Online softmax over incoming edges; head-mean + bias at the end.
template<bool RELU>
__global__ __launch_bounds__(256) void gat_gather(
    const float* __restrict__ xh, const float* __restrict__ aS,
    const float* __restrict__ aD, const int* __restrict__ off,
    const int* __restrict__ deg, const int* __restrict__ csr_src,
    const float* __restrict__ bias, float* __restrict__ out, int n)
{
  const int wid  = threadIdx.x >> 6;
  const int lane = threadIdx.x & 63;
  const int node = blockIdx.x * 4 + wid;
  if (node >= n) return;

  const int h = lane >> 3;
  const float adst = aD[(size_t)node * 8 + h];
  const int o = off[node];
  const int d = deg[node];

  float m = -INFINITY, s = 0.f;
  float4 acc = make_float4(0.f, 0.f, 0.f, 0.f);
  const float4* xh4 = reinterpret_cast<const float4*>(xh);

  for (int j = 0; j < d; ++j) {
    const int src = csr_src[o + j];
    float e = aS[(size_t)src * 8 + h] + adst;
    e = (e > 0.f) ? e : 0.2f * e;          // leaky_relu, slope 0.2
    const float mn = fmaxf(m, e);
    const float sc = expf(m - mn);         // first iter: expf(-inf) = 0
    const float p  = expf(e - mn);
    const float4 xv = xh4[(size_t)src * 64 + lane];
    s = s * sc + p;
    acc.x = acc.x * sc + p * xv.x;
    acc.y = acc.y * sc + p * xv.y;
    acc.z = acc.z * sc + p * xv.z;
    acc.w = acc.w * sc + p * xv.w;
    m = mn;
  }

  const float inv = 1.f / s;               // per-head normalization
  acc.x *= inv; acc.y *= inv; acc.z *= inv; acc.w *= inv;

  // sum over heads: lanes differing in bits 3..5 hold same c, different h
  #pragma unroll
  for (int msk = 8; msk <= 32; msk <<= 1) {
    acc.x += __shfl_xor(acc.x, msk);
    acc.y += __shfl_xor(acc.y, msk);
    acc.z += __shfl_xor(acc.z, msk);
    acc.w += __shfl_xor(acc.w, msk);
  }

  if (lane < 8) {
    const float4 b4 = reinterpret_cast<const float4*>(bias)[lane];
    float4 o4;
    o4.x = acc.x * 0.125f + b4.x;
    o4.y = acc.y * 0.125f + b4.y;
    o4.z = acc.z * 0.125f + b4.z;
    o4.w = acc.w * 0.125f + b4.w;
    if (RELU) {
      o4.x = fmaxf(o4.x, 0.f); o4.y = fmaxf(o4.y, 0.f);
      o4.z = fmaxf(o4.z, 0.f); o4.w = fmaxf(o4.w, 0.f);
    }
    reinterpret_cast<float4*>(out + (size_t)node * 32)[lane] = o4;
  }
}

// ================================ decoder ==================================
// 8 lanes per candidate pair: 32-dim dot product of z rows.
__global__ __launch_bounds__(256) void decode_kernel(
    const float* __restrict__ z, const int* __restrict__ eli,
    float* __restrict__ out, int el)
{
  const int t = blockIdx.x * blockDim.x + threadIdx.x;
  const int pair = t >> 3;
  const int sub  = t & 7;
  if (pair >= el) return;
  const int a = eli[pair];
  const int b = eli[el + pair];
  const float4* z4 = reinterpret_cast<const float4*>(z);
  const float4 va = z4[(size_t)a * 8 + sub];
  const float4 vb = z4[(size_t)b * 8 + sub];
  float dp = va.x * vb.x + va.y * vb.y + va.z * vb.z + va.w * vb.w;
  dp += __shfl_xor(dp, 1);
  dp += __shfl_xor(dp, 2);
  dp += __shfl_xor(dp, 4);
  if (sub == 0) out[pair] = dp;
}

// ================================ launcher =================================
extern "C" void kernel_launch(void* const* d_in, const int* in_sizes, int n_in,
                              void* d_out, int out_size, void* d_ws, size_t ws_size,
                              hipStream_t stream)
{
  const float* x   = (const float*)d_in[0];
  const int*   ei  = (const int*)  d_in[1];
  const int*   eli = (const int*)  d_in[2];
  const float* W1  = (const float*)d_in[3];
  const float* as1 = (const float*)d_in[4];
  const float* ad1 = (const float*)d_in[5];
  const float* b1  = (const float*)d_in[6];
  const float* W2  = (const float*)d_in[7];
  const float* as2 = (const float*)d_in[8];
  const float* ad2 = (const float*)d_in[9];
  const float* b2  = (const float*)d_in[10];
  float* out = (float*)d_out;

  const int n  = in_sizes[0] / 128;   // 50000
  const int e  = in_sizes[1] / 2;     // 400000
  const int el = in_sizes[2] / 2;     // 100000
  const int et = e + n;               // edges incl. self loops

  // workspace carve-up (all chunks 16B-aligned)
  char* p = (char*)d_ws;
  float* xh      = (float*)p; p += (size_t)n * 256 * 4;  // 51.2 MB (both layers)
  float* aS      = (float*)p; p += (size_t)n * 8 * 4;
  float* aD      = (float*)p; p += (size_t)n * 8 * 4;
  int*   deg     = (int*)  p; p += (size_t)n * 4;
  int*   off     = (int*)  p; p += (size_t)n * 4;
  int*   cursor  = (int*)  p; p += (size_t)n * 4;
  int*   csr_src = (int*)  p; p += (size_t)et * 4;
  float* h1      = (float*)p; p += (size_t)n * 32 * 4;
  float* z       = (float*)p; p += (size_t)n * 32 * 4;

  hipMemsetAsync(deg, 0, (size_t)n * 4, stream);

  // CSR build (independent of GEMM1, shared by both layers)
  count_kernel<<<(et + 255) / 256, 256, 0, stream>>>(ei, deg, e, n);
  scan_kernel<<<1, 1024, 0, stream>>>(deg, off, cursor, n);
  scatter_kernel<<<(et + 255) / 256, 256, 0, stream>>>(ei, cursor, csr_src, e, n);

  // layer 1
  gemm_att<128><<<(n + 15) / 16, 256, 0, stream>>>(x, W1, as1, ad1, xh, aS, aD, n);
  gat_gather<true><<<(n + 3) / 4, 256, 0, stream>>>(xh, aS, aD, off, deg, csr_src,
                                                    b1, h1, n);
  // layer 2
  gemm_att<32><<<(n + 15) / 16, 256, 0, stream>>>(h1, W2, as2, ad2, xh, aS, aD, n);
  gat_gather<false><<<(n + 3) / 4, 256, 0, stream>>>(xh, aS, aD, off, deg, csr_src,
                                                     b2, z, n);
  // decoder
  decode_kernel<<<(el * 8 + 255) / 256, 256, 0, stream>>>(z, eli, out, el);
}

// Round 2
// 296.883 us; speedup vs baseline: 1.2805x; 1.2805x over previous
//
#include <hip/hip_runtime.h>
#include <math.h>

// ---------------------------------------------------------------------------
//   N=50000 nodes, E=400000 edges (+N self loops), EL=100000 label pairs
//   H=8 heads, IN=128, HID=32, OUT=32  -> H*C = 256 columns in both GEMMs
// ---------------------------------------------------------------------------

// ======================= GEMM + attention logits ===========================
// xh = X @ W  (n x K)@(K x 256);  aS/aD[n][h] = sum_c xh[n][h*32+c]*att[h][c]
// Block: 256 threads -> tile 32 rows x 256 cols; thread = 8 rows x 4 cols.
template<int K>
__global__ __launch_bounds__(256) void gemm_att(
    const float* __restrict__ X, const float* __restrict__ W,
    const float* __restrict__ attS, const float* __restrict__ attD,
    float* __restrict__ xh, float* __restrict__ aS, float* __restrict__ aD,
    int n)
{
  __shared__ float xs[32][K];     // 32 rows of X  (K=128 -> 16 KB)
  __shared__ float wsm[32][256];  // K-chunk of W  (32 KB)

  const int tid = threadIdx.x;
  const int tc  = tid & 63;   // cols tc*4 .. tc*4+3
  const int tr  = tid >> 6;   // rows tr*8 .. tr*8+7
  const int rowBase = blockIdx.x * 32;

  // --- load X tile (zero-pad OOB rows) ---
  constexpr int RK4 = K / 4;
  constexpr int XF4 = 32 * RK4;
  for (int i = tid; i < XF4; i += 256) {
    const int r  = i / RK4;
    const int c4 = i % RK4;
    const int row = rowBase + r;
    float4 v = make_float4(0.f, 0.f, 0.f, 0.f);
    if (row < n) v = reinterpret_cast<const float4*>(X + (size_t)row * K)[c4];
    reinterpret_cast<float4*>(&xs[r][0])[c4] = v;
  }

  float acc[8][4] = {};

  constexpr int NCHUNK = K / 32;
  for (int kc = 0; kc < NCHUNK; ++kc) {
    __syncthreads();
    // load W chunk rows kc*32..+31 (2048 float4)
    #pragma unroll
    for (int p = 0; p < 8; ++p) {
      const int i4 = p * 256 + tid;
      const int k  = i4 >> 6;
      const int c4 = i4 & 63;
      reinterpret_cast<float4*>(&wsm[k][0])[c4] =
          reinterpret_cast<const float4*>(W + (size_t)(kc * 32 + k) * 256)[c4];
    }
    __syncthreads();

    #pragma unroll
    for (int k4 = 0; k4 < 8; ++k4) {
      float4 wv[4];
      #pragma unroll
      for (int kk = 0; kk < 4; ++kk)
        wv[kk] = reinterpret_cast<float4*>(&wsm[k4 * 4 + kk][0])[tc];
      #pragma unroll
      for (int r = 0; r < 8; ++r) {
        const float4 xv = reinterpret_cast<float4*>(&xs[tr * 8 + r][0])[kc * 8 + k4];
        const float xk[4] = {xv.x, xv.y, xv.z, xv.w};
        #pragma unroll
        for (int kk = 0; kk < 4; ++kk) {
          acc[r][0] += xk[kk] * wv[kk].x;
          acc[r][1] += xk[kk] * wv[kk].y;
          acc[r][2] += xk[kk] * wv[kk].z;
          acc[r][3] += xk[kk] * wv[kk].w;
        }
      }
    }
  }

  // --- epilogue: store xh, reduce attention logits over c within head ---
  const int h    = tc >> 3;
  const int csub = (tc & 7) * 4;
  float sa[4], da[4];
  #pragma unroll
  for (int j = 0; j < 4; ++j) {
    sa[j] = attS[h * 32 + csub + j];
    da[j] = attD[h * 32 + csub + j];
  }

  #pragma unroll
  for (int r = 0; r < 8; ++r) {
    const int row = rowBase + tr * 8 + r;
    if (row >= n) continue;
    float4 o;
    o.x = acc[r][0]; o.y = acc[r][1]; o.z = acc[r][2]; o.w = acc[r][3];
    reinterpret_cast<float4*>(xh + (size_t)row * 256)[tc] = o;

    float ps = acc[r][0] * sa[0] + acc[r][1] * sa[1] + acc[r][2] * sa[2] + acc[r][3] * sa[3];
    float pd = acc[r][0] * da[0] + acc[r][1] * da[1] + acc[r][2] * da[2] + acc[r][3] * da[3];
    #pragma unroll
    for (int msk = 1; msk <= 4; msk <<= 1) {
      ps += __shfl_xor(ps, msk);
      pd += __shfl_xor(pd, msk);
    }
    if ((tc & 7) == 0) {
      aS[(size_t)row * 8 + h] = ps;
      aD[(size_t)row * 8 + h] = pd;
    }
  }
}

// ============================ CSR construction =============================
__global__ void count_kernel(const int* __restrict__ ei, int* __restrict__ deg,
                             int E_, int n) {
  const int i = blockIdx.x * blockDim.x + threadIdx.x;
  const int Et = E_ + n;
  if (i >= Et) return;
  const int dst = (i < E_) ? ei[E_ + i] : (i - E_);
  atomicAdd(&deg[dst], 1);
}

// --- multi-block exclusive scan of deg -> off (and cursor copy) ---
// pass 1: per-block (2048 elems) sums
__global__ __launch_bounds__(256) void scan_part(const int* __restrict__ deg,
                                                 int* __restrict__ part, int n) {
  __shared__ int red[256];
  const int tid = threadIdx.x;
  int s = 0;
  #pragma unroll
  for (int j = 0; j < 8; ++j) {
    const int idx = blockIdx.x * 2048 + j * 256 + tid;
    if (idx < n) s += deg[idx];
  }
  red[tid] = s;
  __syncthreads();
  for (int o = 128; o > 0; o >>= 1) {
    if (tid < o) red[tid] += red[tid + o];
    __syncthreads();
  }
  if (tid == 0) part[blockIdx.x] = red[0];
}

// pass 2: each block recomputes its prefix from part[] then local scan
__global__ __launch_bounds__(256) void scan_fin(
    const int* __restrict__ deg, const int* __restrict__ part,
    int* __restrict__ off, int* __restrict__ cursor, int n, int nblk) {
  __shared__ int sd[256];
  __shared__ int s_pref;
  const int tid = threadIdx.x;
  if (tid == 0) {
    int p = 0;
    for (int i = 0; i < blockIdx.x; ++i) p += part[i];
    s_pref = p;
  }
  const int base = blockIdx.x * 2048 + tid * 8;
  int v[8];
  int tsum = 0;
  #pragma unroll
  for (int j = 0; j < 8; ++j) {
    const int idx = base + j;
    v[j] = (idx < n) ? deg[idx] : 0;
    tsum += v[j];
  }
  sd[tid] = tsum;
  __syncthreads();
  for (int o = 1; o < 256; o <<= 1) {
    const int t = (tid >= o) ? sd[tid - o] : 0;
    __syncthreads();
    sd[tid] += t;
    __syncthreads();
  }
  int start = s_pref + sd[tid] - tsum;
  #pragma unroll
  for (int j = 0; j < 8; ++j) {
    const int idx = base + j;
    if (idx < n) { off[idx] = start; cursor[idx] = start; }
    start += v[j];
  }
}

__global__ void scatter_kernel(const int* __restrict__ ei, int* __restrict__ cursor,
                               int* __restrict__ csr_src, int E_, int n) {
  const int i = blockIdx.x * blockDim.x + threadIdx.x;
  const int Et = E_ + n;
  if (i >= Et) return;
  int src, dst;
  if (i < E_) { src = ei[i]; dst = ei[E_ + i]; }
  else        { src = i - E_; dst = i - E_; }
  const int pos = atomicAdd(&cursor[dst], 1);
  csr_src[pos] = src;
}

// ===================== per-destination gather + softmax ====================
// One wave per node; lane owns 4 channels of flattened 256=(h*32+c).
// Logits are O(1) -> exp without max-subtraction is safe and shift-invariant.
template<bool RELU>
__global__ __launch_bounds__(256) void gat_gather(
    const float* __restrict__ xh, const float* __restrict__ aS,
    const float* __restrict__ aD, const int* __restrict__ off,
    const int* __restrict__ deg, const int* __restrict__ csr_src,
    const float* __restrict__ bias, float* __restrict__ out, int n)
{
  const int wid  = threadIdx.x >> 6;
  const int lane = threadIdx.x & 63;
  const int node = blockIdx.x * 4 + wid;
  if (node >= n) return;

  const int h = lane >> 3;
  const float adst = aD[(size_t)node * 8 + h];
  const int o = off[node];
  const int d = deg[node];

  float s = 0.f;
  float4 acc = make_float4(0.f, 0.f, 0.f, 0.f);
  const float4* xh4 = reinterpret_cast<const float4*>(xh);

  int j = 0;
  for (; j + 2 <= d; j += 2) {
    const int s0 = csr_src[o + j];
    const int s1 = csr_src[o + j + 1];
    const float a0 = aS[(size_t)s0 * 8 + h];
    const float a1 = aS[(size_t)s1 * 8 + h];
    const float4 x0 = xh4[(size_t)s0 * 64 + lane];
    const float4 x1 = xh4[(size_t)s1 * 64 + lane];
    float e0 = a0 + adst; e0 = (e0 > 0.f) ? e0 : 0.2f * e0;
    float e1 = a1 + adst; e1 = (e1 > 0.f) ? e1 : 0.2f * e1;
    const float p0 = __expf(e0);
    const float p1 = __expf(e1);
    s += p0 + p1;
    acc.x += p0 * x0.x + p1 * x1.x;
    acc.y += p0 * x0.y + p1 * x1.y;
    acc.z += p0 * x0.z + p1 * x1.z;
    acc.w += p0 * x0.w + p1 * x1.w;
  }
  if (j < d) {
    const int s0 = csr_src[o + j];
    float e0 = aS[(size_t)s0 * 8 + h] + adst;
    e0 = (e0 > 0.f) ? e0 : 0.2f * e0;
    const float p0 = __expf(e0);
    const float4 x0 = xh4[(size_t)s0 * 64 + lane];
    s += p0;
    acc.x += p0 * x0.x; acc.y += p0 * x0.y;
    acc.z += p0 * x0.z; acc.w += p0 * x0.w;
  }

  const float inv = 1.f / s;
  acc.x *= inv; acc.y *= inv; acc.z *= inv; acc.w *= inv;

  // sum over heads: lanes differing in bits 3..5 hold same c, different h
  #pragma unroll
  for (int msk = 8; msk <= 32; msk <<= 1) {
    acc.x += __shfl_xor(acc.x, msk);
    acc.y += __shfl_xor(acc.y, msk);
    acc.z += __shfl_xor(acc.z, msk);
    acc.w += __shfl_xor(acc.w, msk);
  }

  if (lane < 8) {
    const float4 b4 = reinterpret_cast<const float4*>(bias)[lane];
    float4 o4;
    o4.x = acc.x * 0.125f + b4.x;
    o4.y = acc.y * 0.125f + b4.y;
    o4.z = acc.z * 0.125f + b4.z;
    o4.w = acc.w * 0.125f + b4.w;
    if (RELU) {
      o4.x = fmaxf(o4.x, 0.f); o4.y = fmaxf(o4.y, 0.f);
      o4.z = fmaxf(o4.z, 0.f); o4.w = fmaxf(o4.w, 0.f);
    }
    reinterpret_cast<float4*>(out + (size_t)node * 32)[lane] = o4;
  }
}

// ================================ decoder ==================================
__global__ __launch_bounds__(256) void decode_kernel(
    const float* __restrict__ z, const int* __restrict__ eli,
    float* __restrict__ out, int el)
{
  const int t = blockIdx.x * blockDim.x + threadIdx.x;
  const int pair = t >> 3;
  const int sub  = t & 7;
  if (pair >= el) return;
  const int a = eli[pair];
  const int b = eli[el + pair];
  const float4* z4 = reinterpret_cast<const float4*>(z);
  const float4 va = z4[(size_t)a * 8 + sub];
  const float4 vb = z4[(size_t)b * 8 + sub];
  float dp = va.x * vb.x + va.y * vb.y + va.z * vb.z + va.w * vb.w;
  dp += __shfl_xor(dp, 1);
  dp += __shfl_xor(dp, 2);
  dp += __shfl_xor(dp, 4);
  if (sub == 0) out[pair] = dp;
}

// ================================ launcher =================================
extern "C" void kernel_launch(void* const* d_in, const int* in_sizes, int n_in,
                              void* d_out, int out_size, void* d_ws, size_t ws_size,
                              hipStream_t stream)
{
  const float* x   = (const float*)d_in[0];
  const int*   ei  = (const int*)  d_in[1];
  const int*   eli = (const int*)  d_in[2];
  const float* W1  = (const float*)d_in[3];
  const float* as1 = (const float*)d_in[4];
  const float* ad1 = (const float*)d_in[5];
  const float* b1  = (const float*)d_in[6];
  const float* W2  = (const float*)d_in[7];
  const float* as2 = (const float*)d_in[8];
  const float* ad2 = (const float*)d_in[9];
  const float* b2  = (const float*)d_in[10];
  float* out = (float*)d_out;

  const int n  = in_sizes[0] / 128;   // 50000
  const int e  = in_sizes[1] / 2;     // 400000
  const int el = in_sizes[2] / 2;     // 100000
  const int et = e + n;

  // workspace carve-up (16B-aligned chunks)
  char* p = (char*)d_ws;
  float* xh      = (float*)p; p += (size_t)n * 256 * 4;  // 51.2 MB
  float* aS      = (float*)p; p += (size_t)n * 8 * 4;
  float* aD      = (float*)p; p += (size_t)n * 8 * 4;
  int*   deg     = (int*)  p; p += (size_t)n * 4;
  int*   off     = (int*)  p; p += (size_t)n * 4;
  int*   cursor  = (int*)  p; p += (size_t)n * 4;
  int*   part    = (int*)  p; p += 128 * 4;
  int*   csr_src = (int*)  p; p += (size_t)et * 4;
  float* h1      = (float*)p; p += (size_t)n * 32 * 4;
  float* z       = (float*)p; p += (size_t)n * 32 * 4;

  const int nblk = (n + 2047) / 2048;

  hipMemsetAsync(deg, 0, (size_t)n * 4, stream);

  // CSR build
  count_kernel<<<(et + 255) / 256, 256, 0, stream>>>(ei, deg, e, n);
  scan_part<<<nblk, 256, 0, stream>>>(deg, part, n);
  scan_fin<<<nblk, 256, 0, stream>>>(deg, part, off, cursor, n, nblk);
  scatter_kernel<<<(et + 255) / 256, 256, 0, stream>>>(ei, cursor, csr_src, e, n);

  // layer 1
  gemm_att<128><<<(n + 31) / 32, 256, 0, stream>>>(x, W1, as1, ad1, xh, aS, aD, n);
  gat_gather<true><<<(n + 3) / 4, 256, 0, stream>>>(xh, aS, aD, off, deg, csr_src,
                                                    b1, h1, n);
  // layer 2
  gemm_att<32><<<(n + 31) / 32, 256, 0, stream>>>(h1, W2, as2, ad2, xh, aS, aD, n);
  gat_gather<false><<<(n + 3) / 4, 256, 0, stream>>>(xh, aS, aD, off, deg, csr_src,
                                                     b2, z, n);
  // decoder
  decode_kernel<<<(el * 8 + 255) / 256, 256, 0, stream>>>(z, eli, out, el);
}

// Round 3
// 292.176 us; speedup vs baseline: 1.3012x; 1.0161x over previous
//
#include <hip/hip_runtime.h>
#include <math.h>
#include <stdint.h>

// ---------------------------------------------------------------------------
//   N=50000 nodes, E=400000 edges (+N self loops), EL=100000 label pairs
//   H=8 heads, IN=128, HID=32, OUT=32  -> H*C = 256 columns in both GEMMs
// ---------------------------------------------------------------------------

typedef __attribute__((ext_vector_type(8))) short bf16x8;   // 8 bf16 = 4 VGPR
typedef __attribute__((ext_vector_type(4))) float f32x4;

__device__ __forceinline__ short bf16_rn(float x) {
  uint32_t u = __float_as_uint(x);
  uint32_t r = (u + 0x7FFFu + ((u >> 16) & 1u)) >> 16;
  return (short)r;
}
__device__ __forceinline__ float bf16_f(short h) {
  return __uint_as_float(((uint32_t)(uint16_t)h) << 16);
}

// ================= W pre-transpose: [K][256] f32 -> [K/8][256][8] bf16 =====
// hi = rn(w), lo = rn(w - hi). grid = K/8 blocks of 256 threads (1 col each).
__global__ __launch_bounds__(256) void wtrans(
    const float* __restrict__ W, short* __restrict__ Whi,
    short* __restrict__ Wlo)
{
  const int col = threadIdx.x;
  const int chunk = blockIdx.x;
  float w[8];
  #pragma unroll
  for (int e = 0; e < 8; ++e)
    w[e] = W[(size_t)(chunk * 8 + e) * 256 + col];
  bf16x8 vh, vl;
  #pragma unroll
  for (int e = 0; e < 8; ++e) {
    const short h = bf16_rn(w[e]);
    vh[e] = h;
    vl[e] = bf16_rn(w[e] - bf16_f(h));
  }
  *(bf16x8*)(Whi + ((size_t)chunk * 256 + col) * 8) = vh;
  *(bf16x8*)(Wlo + ((size_t)chunk * 256 + col) * 8) = vl;
}

// ============== split-bf16 MFMA GEMM + fused attention logits ==============
// xh = X(n x K) @ W(K x 256) via 3-pass split-bf16 16x16x32 MFMA.
// Wave = 16 rows x 256 cols (16 col-tiles, f32x4 acc each). Block = 4 waves.
// A-frag: lane holds row (lane&15), k = kc*32 + (lane>>4)*8 + e  (e=0..7).
// B-frag: lane holds col (lane&15) of tile, same k set (pre-swizzled layout).
// D: col = lane&15, row = (lane>>4)*4 + reg   [HW-verified layout]
template<int K>
__global__ __launch_bounds__(256) void mfma_gemm_att(
    const float* __restrict__ X, const short* __restrict__ Whi,
    const short* __restrict__ Wlo, const float* __restrict__ attS,
    const float* __restrict__ attD, float* __restrict__ xh,
    float* __restrict__ aS, float* __restrict__ aD, int n)
{
  const int lane = threadIdx.x & 63;
  const int wid  = threadIdx.x >> 6;
  const int lr   = lane & 15;
  const int lg   = lane >> 4;
  const int r0   = (blockIdx.x * 4 + wid) * 16;
  if (r0 >= n) return;

  f32x4 acc[16];
  #pragma unroll
  for (int i = 0; i < 16; ++i) acc[i] = (f32x4){0.f, 0.f, 0.f, 0.f};

  const int arow = r0 + lr;
  const bool aok = arow < n;
  const float* xp = X + (size_t)arow * K;

  #pragma unroll
  for (int kc = 0; kc < K / 32; ++kc) {
    float a[8];
    if (aok) {
      const float4 p0 = *(const float4*)(xp + kc * 32 + lg * 8);
      const float4 p1 = *(const float4*)(xp + kc * 32 + lg * 8 + 4);
      a[0] = p0.x; a[1] = p0.y; a[2] = p0.z; a[3] = p0.w;
      a[4] = p1.x; a[5] = p1.y; a[6] = p1.z; a[7] = p1.w;
    } else {
      #pragma unroll
      for (int e = 0; e < 8; ++e) a[e] = 0.f;
    }
    bf16x8 Ah, Al;
    #pragma unroll
    for (int e = 0; e < 8; ++e) {
      const short h = bf16_rn(a[e]);
      Ah[e] = h;
      Al[e] = bf16_rn(a[e] - bf16_f(h));
    }
    const bf16x8* bh = (const bf16x8*)(Whi + ((size_t)(kc * 4 + lg) * 256) * 8);
    const bf16x8* bl = (const bf16x8*)(Wlo + ((size_t)(kc * 4 + lg) * 256) * 8);
    #pragma unroll
    for (int nt = 0; nt < 16; ++nt) {
      const bf16x8 Bh = bh[nt * 16 + lr];
      const bf16x8 Bl = bl[nt * 16 + lr];
      acc[nt] = __builtin_amdgcn_mfma_f32_16x16x32_bf16(Ah, Bh, acc[nt], 0, 0, 0);
      acc[nt] = __builtin_amdgcn_mfma_f32_16x16x32_bf16(Ah, Bl, acc[nt], 0, 0, 0);
      acc[nt] = __builtin_amdgcn_mfma_f32_16x16x32_bf16(Al, Bh, acc[nt], 0, 0, 0);
    }
  }

  // --- epilogue: xh store + per-head attention logits ---
  float sa[16], da[16];
  #pragma unroll
  for (int nt = 0; nt < 16; ++nt) {
    const int h = nt >> 1, c = (nt & 1) * 16 + lr;
    sa[nt] = attS[h * 32 + c];
    da[nt] = attD[h * 32 + c];
  }

  #pragma unroll
  for (int r = 0; r < 4; ++r) {
    const int orow = r0 + lg * 4 + r;
    const bool ook = orow < n;
    if (ook) {
      float* xo = xh + (size_t)orow * 256 + lr;
      #pragma unroll
      for (int nt = 0; nt < 16; ++nt) xo[nt * 16] = acc[nt][r];
    }
    #pragma unroll
    for (int h = 0; h < 8; ++h) {
      float vs = acc[2 * h][r] * sa[2 * h] + acc[2 * h + 1][r] * sa[2 * h + 1];
      float vd = acc[2 * h][r] * da[2 * h] + acc[2 * h + 1][r] * da[2 * h + 1];
      #pragma unroll
      for (int m = 1; m <= 8; m <<= 1) {
        vs += __shfl_xor(vs, m);
        vd += __shfl_xor(vd, m);
      }
      if (lr == 0 && ook) {
        aS[(size_t)orow * 8 + h] = vs;
        aD[(size_t)orow * 8 + h] = vd;
      }
    }
  }
}

// ============================ CSR construction =============================
__global__ void count_kernel(const int* __restrict__ ei, int* __restrict__ deg,
                             int E_, int n) {
  const int i = blockIdx.x * blockDim.x + threadIdx.x;
  const int Et = E_ + n;
  if (i >= Et) return;
  const int dst = (i < E_) ? ei[E_ + i] : (i - E_);
  atomicAdd(&deg[dst], 1);
}

__global__ __launch_bounds__(256) void scan_part(const int* __restrict__ deg,
                                                 int* __restrict__ part, int n) {
  __shared__ int red[256];
  const int tid = threadIdx.x;
  int s = 0;
  #pragma unroll
  for (int j = 0; j < 8; ++j) {
    const int idx = blockIdx.x * 2048 + j * 256 + tid;
    if (idx < n) s += deg[idx];
  }
  red[tid] = s;
  __syncthreads();
  for (int o = 128; o > 0; o >>= 1) {
    if (tid < o) red[tid] += red[tid + o];
    __syncthreads();
  }
  if (tid == 0) part[blockIdx.x] = red[0];
}

__global__ __launch_bounds__(256) void scan_fin(
    const int* __restrict__ deg, const int* __restrict__ part,
    int* __restrict__ off, int* __restrict__ cursor, int n, int nblk) {
  __shared__ int sd[256];
  __shared__ int s_pref;
  const int tid = threadIdx.x;
  if (tid == 0) {
    int p = 0;
    for (int i = 0; i < blockIdx.x; ++i) p += part[i];
    s_pref = p;
  }
  const int base = blockIdx.x * 2048 + tid * 8;
  int v[8];
  int tsum = 0;
  #pragma unroll
  for (int j = 0; j < 8; ++j) {
    const int idx = base + j;
    v[j] = (idx < n) ? deg[idx] : 0;
    tsum += v[j];
  }
  sd[tid] = tsum;
  __syncthreads();
  for (int o = 1; o < 256; o <<= 1) {
    const int t = (tid >= o) ? sd[tid - o] : 0;
    __syncthreads();
    sd[tid] += t;
    __syncthreads();
  }
  int start = s_pref + sd[tid] - tsum;
  #pragma unroll
  for (int j = 0; j < 8; ++j) {
    const int idx = base + j;
    if (idx < n) { off[idx] = start; cursor[idx] = start; }
    start += v[j];
  }
}

__global__ void scatter_kernel(const int* __restrict__ ei, int* __restrict__ cursor,
                               int* __restrict__ csr_src, int E_, int n) {
  const int i = blockIdx.x * blockDim.x + threadIdx.x;
  const int Et = E_ + n;
  if (i >= Et) return;
  int src, dst;
  if (i < E_) { src = ei[i]; dst = ei[E_ + i]; }
  else        { src = i - E_; dst = i - E_; }
  const int pos = atomicAdd(&cursor[dst], 1);
  csr_src[pos] = src;
}

// ===================== per-destination gather + softmax ====================
// One wave per node; lane owns 4 channels of flattened 256=(h*32+c).
template<bool RELU>
__global__ __launch_bounds__(256) void gat_gather(
    const float* __restrict__ xh, const float* __restrict__ aS,
    const float* __restrict__ aD, const int* __restrict__ off,
    const int* __restrict__ deg, const int* __restrict__ csr_src,
    const float* __restrict__ bias, float* __restrict__ out, int n)
{
  const int wid  = threadIdx.x >> 6;
  const int lane = threadIdx.x & 63;
  const int node = blockIdx.x * 4 + wid;
  if (node >= n) return;

  const int h = lane >> 3;
  const float adst = aD[(size_t)node * 8 + h];
  const int o = off[node];
  const int d = deg[node];

  float s = 0.f;
  float4 acc = make_float4(0.f, 0.f, 0.f, 0.f);
  const float4* xh4 = reinterpret_cast<const float4*>(xh);

  int j = 0;
  for (; j + 4 <= d; j += 4) {
    int si[4];
    #pragma unroll
    for (int q = 0; q < 4; ++q) si[q] = csr_src[o + j + q];
    float av[4];
    float4 xv[4];
    #pragma unroll
    for (int q = 0; q < 4; ++q) {
      av[q] = aS[(size_t)si[q] * 8 + h];
      xv[q] = xh4[(size_t)si[q] * 64 + lane];
    }
    #pragma unroll
    for (int q = 0; q < 4; ++q) {
      float e = av[q] + adst;
      e = (e > 0.f) ? e : 0.2f * e;
      const float p = __expf(e);
      s += p;
      acc.x += p * xv[q].x;
      acc.y += p * xv[q].y;
      acc.z += p * xv[q].z;
      acc.w += p * xv[q].w;
    }
  }
  for (; j < d; ++j) {
    const int s0 = csr_src[o + j];
    float e0 = aS[(size_t)s0 * 8 + h] + adst;
    e0 = (e0 > 0.f) ? e0 : 0.2f * e0;
    const float p0 = __expf(e0);
    const float4 x0 = xh4[(size_t)s0 * 64 + lane];
    s += p0;
    acc.x += p0 * x0.x; acc.y += p0 * x0.y;
    acc.z += p0 * x0.z; acc.w += p0 * x0.w;
  }

  const float inv = 1.f / s;
  acc.x *= inv; acc.y *= inv; acc.z *= inv; acc.w *= inv;

  #pragma unroll
  for (int msk = 8; msk <= 32; msk <<= 1) {
    acc.x += __shfl_xor(acc.x, msk);
    acc.y += __shfl_xor(acc.y, msk);
    acc.z += __shfl_xor(acc.z, msk);
    acc.w += __shfl_xor(acc.w, msk);
  }

  if (lane < 8) {
    const float4 b4 = reinterpret_cast<const float4*>(bias)[lane];
    float4 o4;
    o4.x = acc.x * 0.125f + b4.x;
    o4.y = acc.y * 0.125f + b4.y;
    o4.z = acc.z * 0.125f + b4.z;
    o4.w = acc.w * 0.125f + b4.w;
    if (RELU) {
      o4.x = fmaxf(o4.x, 0.f); o4.y = fmaxf(o4.y, 0.f);
      o4.z = fmaxf(o4.z, 0.f); o4.w = fmaxf(o4.w, 0.f);
    }
    reinterpret_cast<float4*>(out + (size_t)node * 32)[lane] = o4;
  }
}

// ================================ decoder ==================================
__global__ __launch_bounds__(256) void decode_kernel(
    const float* __restrict__ z, const int* __restrict__ eli,
    float* __restrict__ out, int el)
{
  const int t = blockIdx.x * blockDim.x + threadIdx.x;
  const int pair = t >> 3;
  const int sub  = t & 7;
  if (pair >= el) return;
  const int a = eli[pair];
  const int b = eli[el + pair];
  const float4* z4 = reinterpret_cast<const float4*>(z);
  const float4 va = z4[(size_t)a * 8 + sub];
  const float4 vb = z4[(size_t)b * 8 + sub];
  float dp = va.x * vb.x + va.y * vb.y + va.z * vb.z + va.w * vb.w;
  dp += __shfl_xor(dp, 1);
  dp += __shfl_xor(dp, 2);
  dp += __shfl_xor(dp, 4);
  if (sub == 0) out[pair] = dp;
}

// ================================ launcher =================================
extern "C" void kernel_launch(void* const* d_in, const int* in_sizes, int n_in,
                              void* d_out, int out_size, void* d_ws, size_t ws_size,
                              hipStream_t stream)
{
  const float* x   = (const float*)d_in[0];
  const int*   ei  = (const int*)  d_in[1];
  const int*   eli = (const int*)  d_in[2];
  const float* W1  = (const float*)d_in[3];
  const float* as1 = (const float*)d_in[4];
  const float* ad1 = (const float*)d_in[5];
  const float* b1  = (const float*)d_in[6];
  const float* W2  = (const float*)d_in[7];
  const float* as2 = (const float*)d_in[8];
  const float* ad2 = (const float*)d_in[9];
  const float* b2  = (const float*)d_in[10];
  float* out = (float*)d_out;

  const int n  = in_sizes[0] / 128;   // 50000
  const int e  = in_sizes[1] / 2;     // 400000
  const int el = in_sizes[2] / 2;     // 100000
  const int et = e + n;

  // workspace carve-up (16B-aligned chunks)
  char* p = (char*)d_ws;
  float* xh      = (float*)p; p += (size_t)n * 256 * 4;  // 51.2 MB
  float* aS      = (float*)p; p += (size_t)n * 8 * 4;
  float* aD      = (float*)p; p += (size_t)n * 8 * 4;
  int*   deg     = (int*)  p; p += (size_t)n * 4;
  int*   off     = (int*)  p; p += (size_t)n * 4;
  int*   cursor  = (int*)  p; p += (size_t)n * 4;
  int*   part    = (int*)  p; p += 128 * 4;
  int*   csr_src = (int*)  p; p += (size_t)et * 4;
  float* h1      = (float*)p; p += (size_t)n * 32 * 4;
  float* z       = (float*)p; p += (size_t)n * 32 * 4;
  short* W1hi    = (short*)p; p += (size_t)16 * 256 * 8 * 2;
  short* W1lo    = (short*)p; p += (size_t)16 * 256 * 8 * 2;
  short* W2hi    = (short*)p; p += (size_t)4 * 256 * 8 * 2;
  short* W2lo    = (short*)p; p += (size_t)4 * 256 * 8 * 2;

  const int nblk = (n + 2047) / 2048;
  const int gblk = (n + 63) / 64;     // mfma gemm: 4 waves x 16 rows

  hipMemsetAsync(deg, 0, (size_t)n * 4, stream);

  // CSR build + W pre-transposes
  count_kernel<<<(et + 255) / 256, 256, 0, stream>>>(ei, deg, e, n);
  scan_part<<<nblk, 256, 0, stream>>>(deg, part, n);
  scan_fin<<<nblk, 256, 0, stream>>>(deg, part, off, cursor, n, nblk);
  scatter_kernel<<<(et + 255) / 256, 256, 0, stream>>>(ei, cursor, csr_src, e, n);
  wtrans<<<16, 256, 0, stream>>>(W1, W1hi, W1lo);
  wtrans<<<4, 256, 0, stream>>>(W2, W2hi, W2lo);

  // layer 1
  mfma_gemm_att<128><<<gblk, 256, 0, stream>>>(x, W1hi, W1lo, as1, ad1,
                                               xh, aS, aD, n);
  gat_gather<true><<<(n + 3) / 4, 256, 0, stream>>>(xh, aS, aD, off, deg, csr_src,
                                                    b1, h1, n);
  // layer 2
  mfma_gemm_att<32><<<gblk, 256, 0, stream>>>(h1, W2hi, W2lo, as2, ad2,
                                              xh, aS, aD, n);
  gat_gather<false><<<(n + 3) / 4, 256, 0, stream>>>(xh, aS, aD, off, deg, csr_src,
                                                     b2, z, n);
  // decoder
  decode_kernel<<<(el * 8 + 255) / 256, 256, 0, stream>>>(z, eli, out, el);
}